// Round 9
// baseline (124.955 us; speedup 1.0000x reference)
//
#include <hip/hip_runtime.h>
#include <hip/hip_bf16.h>
#include <math.h>

// vec[b,e] = sum_s softmax_s( tanh(theta@w.T [b,:] + h[b,s,:]@u) @ v ) * h[b,s,e]
// B=64, S=2048, E=256, T=100
// R9: cross-tile pipelined fused kernel. Grid 512 (2 blocks/CU), each block
//     owns 8 consecutive 32-row tiles of one b. u-slice in 128 VGPRs (loaded
//     once, amortized 8x). T14 split-stage: issue tile c+1 global loads at
//     iter start; pack+ds_write after tile c's last LDS read barrier.
//     Single bf16 LDS tile buffer; ~220 VGPR, no spill.

#define E_DIM 256
#define GM 32        // s-rows per tile
#define NC 8         // tiles per block

typedef __bf16 bf16x8 __attribute__((ext_vector_type(8)));
typedef float  f32x4  __attribute__((ext_vector_type(4)));

__device__ __forceinline__ unsigned short f2bf(float x) {
    return __builtin_bit_cast(unsigned short, (__bf16)x);
}
__device__ __forceinline__ float bf2f(unsigned short b) {
    return __builtin_bit_cast(float, (unsigned)b << 16);
}

// XOR-swizzle for 512 B bf16 rows: flip 16B-slot bits 4-6 by row&7 (row = byte>>9).
__device__ __forceinline__ unsigned swz(unsigned byte) {
    return byte ^ ((((byte) >> 9) & 7) << 4);
}

// tanh(x) = 1 - 2/(exp(2x)+1); overflow-safe (rcp(inf)=0).
__device__ __forceinline__ float fast_tanh(float x) {
    const float e = __expf(2.0f * x);
    const float r = __builtin_amdgcn_rcpf(e + 1.0f);
    return fmaf(-2.0f, r, 1.0f);
}

// ---------------- Kernel 0 (fused prep): u transpose + theta@w.T ----------------
__global__ __launch_bounds__(256) void k_prep(const float* __restrict__ u,
                                              const float* __restrict__ theta,
                                              const float* __restrict__ w,
                                              unsigned short* __restrict__ u_t,
                                              float* __restrict__ tw,
                                              int T) {
    if (blockIdx.x < E_DIM) {
        const int f = blockIdx.x, e = threadIdx.x;
        u_t[(size_t)f * E_DIM + e] = f2bf(u[(size_t)e * E_DIM + f]);
    } else {
        __shared__ float th[128];
        const int b = blockIdx.x - E_DIM;
        const int e = threadIdx.x;
        if (threadIdx.x < T) th[threadIdx.x] = theta[b * T + threadIdx.x];
        __syncthreads();
        float acc = 0.f;
        for (int t = 0; t < T; ++t) acc = fmaf(th[t], w[e * T + t], acc);
        tw[b * E_DIM + e] = acc;
    }
}

// ---------------- Kernel 1 (fused gate+softmax-partial, pipelined) ----------------
__global__ __launch_bounds__(256, 2) void k_gate_fused(const float* __restrict__ h,
                                                       const unsigned short* __restrict__ u_t,
                                                       const float* __restrict__ tw_,
                                                       const float* __restrict__ v,
                                                       float* __restrict__ partial,
                                                       float* __restrict__ pm,
                                                       float* __restrict__ pd,
                                                       int S, int SC) {
    __shared__ unsigned short hbf[GM * E_DIM];  // 16 KB bf16, swizzled
    __shared__ float red[4][GM];                // 512 B
    __shared__ float exw[GM];                   // 128 B
    __shared__ float pacc[4][E_DIM];            // 4 KB

    const int b   = blockIdx.y;
    const int c0  = blockIdx.x * NC;   // first tile index
    const int tid = threadIdx.x;
    const int w   = tid >> 6;      // wave 0..3
    const int l   = tid & 63;      // lane
    const int lg  = l >> 4;        // k-group 0..3
    const int lc  = l & 15;        // row/col class 0..15
    const int f0w = w * 64;        // wave's f-range base

    char* ldsb = (char*)hbf;

    // ---- preload ENTIRE per-wave u-slice (32 x bf16x8 = 128 VGPR), once ----
    bf16x8 ub[8][4];   // [kt][n]
#pragma unroll
    for (int kt = 0; kt < 8; ++kt)
#pragma unroll
        for (int n = 0; n < 4; ++n)
            ub[kt][n] = *reinterpret_cast<const bf16x8*>(
                u_t + (size_t)(f0w + n * 16 + lc) * E_DIM + kt * 32 + lg * 8);

    // ---- per-block epilogue constants (once) ----
    float tw_f[4], v_f[4];
#pragma unroll
    for (int n = 0; n < 4; ++n) {
        const int f = f0w + n * 16 + lc;
        tw_f[n] = tw_[b * E_DIM + f];
        v_f[n]  = v[f];
    }

    // ---- prologue: stage tile 0 (load -> pack -> swizzled ds_write) ----
    float4 st[8];
    {
        const float* hb0 = h + ((size_t)b * S + (size_t)c0 * GM) * E_DIM;
#pragma unroll
        for (int j = 0; j < 8; ++j)
            st[j] = *reinterpret_cast<const float4*>(hb0 + (size_t)(j * 4 + w) * E_DIM + l * 4);
#pragma unroll
        for (int j = 0; j < 8; ++j) {
            uint2 pk;
            pk.x = (unsigned)f2bf(st[j].x) | ((unsigned)f2bf(st[j].y) << 16);
            pk.y = (unsigned)f2bf(st[j].z) | ((unsigned)f2bf(st[j].w) << 16);
            *reinterpret_cast<uint2*>(ldsb + swz((j * 4 + w) * 512 + l * 8)) = pk;
        }
    }
    __syncthreads();   // tile 0 ready

    for (int c = 0; c < NC; ++c) {
        const int sc = c0 + c;
        const bool pf = (c + 1 < NC);

        // ---- T14 issue-early: global loads for tile c+1 (land during compute) ----
        if (pf) {
            const float* hbn = h + ((size_t)b * S + (size_t)(sc + 1) * GM) * E_DIM;
#pragma unroll
            for (int j = 0; j < 8; ++j)
                st[j] = *reinterpret_cast<const float4*>(hbn + (size_t)(j * 4 + w) * E_DIM + l * 4);
        }

        // ---- K loop: 8 k-steps of 32; A from LDS, B from registers ----
        f32x4 acc[2][4];
#pragma unroll
        for (int m = 0; m < 2; ++m)
#pragma unroll
            for (int n = 0; n < 4; ++n)
                acc[m][n] = (f32x4){0.f, 0.f, 0.f, 0.f};

#pragma unroll
        for (int kt = 0; kt < 8; ++kt) {
            bf16x8 af[2];
#pragma unroll
            for (int m = 0; m < 2; ++m)
                af[m] = *reinterpret_cast<const bf16x8*>(
                    ldsb + swz((m * 16 + lc) * 512 + kt * 64 + lg * 16));
#pragma unroll
            for (int n = 0; n < 4; ++n) {
                acc[0][n] = __builtin_amdgcn_mfma_f32_16x16x32_bf16(af[0], ub[kt][n], acc[0][n], 0, 0, 0);
                acc[1][n] = __builtin_amdgcn_mfma_f32_16x16x32_bf16(af[1], ub[kt][n], acc[1][n], 0, 0, 0);
            }
        }

        // ---- gate epilogue: tanh(z+tw)*v, sum over f (lc-classes then waves) ----
        float part[2][4] = {};   // [m][i]; row = m*16 + lg*4 + i, col-class lc
#pragma unroll
        for (int n = 0; n < 4; ++n)
#pragma unroll
            for (int m = 0; m < 2; ++m)
#pragma unroll
                for (int i = 0; i < 4; ++i)
                    part[m][i] += fast_tanh(acc[m][n][i] + tw_f[n]) * v_f[n];

#pragma unroll
        for (int off = 1; off < 16; off <<= 1)
#pragma unroll
            for (int m = 0; m < 2; ++m)
#pragma unroll
                for (int i = 0; i < 4; ++i)
                    part[m][i] += __shfl_xor(part[m][i], off, 64);

        if (lc == 0) {
#pragma unroll
            for (int m = 0; m < 2; ++m)
#pragma unroll
                for (int i = 0; i < 4; ++i)
                    red[w][m * 16 + lg * 4 + i] = part[m][i];
        }
        __syncthreads();   // B1: red ready

        // ---- block softmax stats: lanes 0..31 own the 32 g values ----
        if (tid < GM) {
            const float g = red[0][tid] + red[1][tid] + red[2][tid] + red[3][tid];
            float mx = g;
#pragma unroll
            for (int off = 1; off < 32; off <<= 1)
                mx = fmaxf(mx, __shfl_xor(mx, off, 64));
            const float ex = __expf(g - mx);
            float d = ex;
#pragma unroll
            for (int off = 1; off < 32; off <<= 1)
                d += __shfl_xor(d, off, 64);
            exw[tid] = ex;
            if (tid == 0) {
                pm[(size_t)b * SC + sc] = mx;
                pd[(size_t)b * SC + sc] = d;
            }
        }
        __syncthreads();   // B2: exw ready

        // ---- weighted partial: wave w sums rows w*8..w*8+7; lane owns 4 e-cols ----
        f32x4 a4 = (f32x4){0.f, 0.f, 0.f, 0.f};
#pragma unroll
        for (int j = 0; j < 8; ++j) {
            const int row = w * 8 + j;
            const float ws = exw[row];
            const uint2 hv = *reinterpret_cast<const uint2*>(ldsb + swz(row * 512 + l * 8));
            a4[0] = fmaf(ws, bf2f((unsigned short)(hv.x & 0xffff)), a4[0]);
            a4[1] = fmaf(ws, bf2f((unsigned short)(hv.x >> 16)),    a4[1]);
            a4[2] = fmaf(ws, bf2f((unsigned short)(hv.y & 0xffff)), a4[2]);
            a4[3] = fmaf(ws, bf2f((unsigned short)(hv.y >> 16)),    a4[3]);
        }
        *reinterpret_cast<f32x4*>(&pacc[w][l * 4]) = a4;
        __syncthreads();   // B3: pacc ready; all reads of tile c done

        const float p = pacc[0][tid] + pacc[1][tid] + pacc[2][tid] + pacc[3][tid];
        partial[((size_t)b * SC + sc) * E_DIM + tid] = p;

        // ---- T14 write-late: pack tile c+1 into LDS (overwrites tile c) ----
        if (pf) {
#pragma unroll
            for (int j = 0; j < 8; ++j) {
                uint2 pk;
                pk.x = (unsigned)f2bf(st[j].x) | ((unsigned)f2bf(st[j].y) << 16);
                pk.y = (unsigned)f2bf(st[j].z) | ((unsigned)f2bf(st[j].w) << 16);
                *reinterpret_cast<uint2*>(ldsb + swz((j * 4 + w) * 512 + l * 8)) = pk;
            }
        }
        __syncthreads();   // B4: tile c+1 ready
    }
}

// ---------------- Kernel 2: exact softmax merge across chunks ----------------
__global__ __launch_bounds__(256) void k_combine(const float* __restrict__ partial,
                                                 const float* __restrict__ pm,
                                                 const float* __restrict__ pd,
                                                 float* __restrict__ out,
                                                 int SC) {
    const int b = blockIdx.x, t = threadIdx.x;
    __shared__ float sm[128], sd[128];
    if (t < SC) {
        sm[t] = pm[(size_t)b * SC + t];
        sd[t] = pd[(size_t)b * SC + t];
    }
    __syncthreads();

    float M = -3.4e38f;
    for (int c = 0; c < SC; ++c) M = fmaxf(M, sm[c]);

    float num = 0.f, den = 0.f;
    for (int c = 0; c < SC; ++c) {
        const float s = __expf(sm[c] - M);
        den = fmaf(s, sd[c], den);
        num = fmaf(s, partial[((size_t)b * SC + c) * E_DIM + t], num);
    }
    out[(size_t)b * E_DIM + t] = num / den;
}

extern "C" void kernel_launch(void* const* d_in, const int* in_sizes, int n_in,
                              void* d_out, int out_size, void* d_ws, size_t ws_size,
                              hipStream_t stream) {
    const float* h     = (const float*)d_in[0];
    const float* theta = (const float*)d_in[1];
    const float* w     = (const float*)d_in[2];
    const float* v     = (const float*)d_in[3];
    const float* u     = (const float*)d_in[4];
    float* out = (float*)d_out;

    const int E = in_sizes[3];              // 256
    const int T = in_sizes[2] / E;          // 100
    const int B = in_sizes[1] / T;          // 64
    const int S = in_sizes[0] / (B * E);    // 2048
    const int SC = S / GM;                  // 64

    float* tw = (float*)d_ws;                                     // [B,E]
    unsigned short* u_t = (unsigned short*)(tw + (size_t)B * E);  // [E,E] bf16
    float* partial = (float*)(u_t + (size_t)E * E);               // [B,SC,E]
    float* pm = partial + (size_t)B * SC * E;                     // [B,SC]
    float* pd = pm + (size_t)B * SC;                              // [B,SC]

    k_prep<<<dim3(E + B), dim3(256), 0, stream>>>(u, theta, w, u_t, tw, T);
    k_gate_fused<<<dim3(SC / NC, B), dim3(256), 0, stream>>>(h, u_t, tw, v, partial, pm, pd, S, SC);
    k_combine<<<dim3(B), dim3(256), 0, stream>>>(partial, pm, pd, out, SC);
}

// Round 10
// 83.310 us; speedup vs baseline: 1.4999x; 1.4999x over previous
//
#include <hip/hip_runtime.h>
#include <hip/hip_bf16.h>
#include <math.h>

// vec[b,e] = sum_s softmax_s( tanh(theta@w.T [b,:] + h[b,s,:]@u) @ v ) * h[b,s,e]
// B=64, S=2048, E=256, T=100
// R10: 8-wave (512-thread) blocks, wave owns 32 f -> ub[8][2] = 64 VGPR only.
//      Total ~100 VGPR < 128 cap of __launch_bounds__(512,4) => 2 blocks/CU,
//      u register-resident, no spill, K-loop pure LDS+MFMA. GM=32, 4096
//      blocks self-stagger => HBM-bound regime.

#define E_DIM 256
#define GM 32        // s-rows per block

typedef __bf16 bf16x8 __attribute__((ext_vector_type(8)));
typedef float  f32x4  __attribute__((ext_vector_type(4)));

__device__ __forceinline__ unsigned short f2bf(float x) {
    return __builtin_bit_cast(unsigned short, (__bf16)x);
}
__device__ __forceinline__ float bf2f(unsigned short b) {
    return __builtin_bit_cast(float, (unsigned)b << 16);
}

// XOR-swizzle for 512 B bf16 rows: flip 16B-slot bits 4-6 by row&7 (row = byte>>9).
__device__ __forceinline__ unsigned swz(unsigned byte) {
    return byte ^ ((((byte) >> 9) & 7) << 4);
}

// tanh(x) = 1 - 2/(exp(2x)+1); overflow-safe (rcp(inf)=0).
__device__ __forceinline__ float fast_tanh(float x) {
    const float e = __expf(2.0f * x);
    const float r = __builtin_amdgcn_rcpf(e + 1.0f);
    return fmaf(-2.0f, r, 1.0f);
}

// ---------------- Kernel 0 (fused prep): u transpose + theta@w.T ----------------
__global__ __launch_bounds__(256) void k_prep(const float* __restrict__ u,
                                              const float* __restrict__ theta,
                                              const float* __restrict__ w,
                                              unsigned short* __restrict__ u_t,
                                              float* __restrict__ tw,
                                              int T) {
    if (blockIdx.x < E_DIM) {
        const int f = blockIdx.x, e = threadIdx.x;
        u_t[(size_t)f * E_DIM + e] = f2bf(u[(size_t)e * E_DIM + f]);
    } else {
        __shared__ float th[128];
        const int b = blockIdx.x - E_DIM;
        const int e = threadIdx.x;
        if (threadIdx.x < T) th[threadIdx.x] = theta[b * T + threadIdx.x];
        __syncthreads();
        float acc = 0.f;
        for (int t = 0; t < T; ++t) acc = fmaf(th[t], w[e * T + t], acc);
        tw[b * E_DIM + e] = acc;
    }
}

// ---------------- Kernel 1 (fused): per (b, s-chunk of 32):
//   g_s = sum_f tanh(tw[b,f] + (h@u)[s,f]) * v[f]      (MFMA, bf16)
//   m = max_s g_s;  ex_s = exp(g_s - m);  d = sum ex_s
//   partial[e] = sum_s ex_s * h[s,e]                   (from resident LDS tile)
// 8 waves; wave w owns f in [32w, 32w+32).
__global__ __launch_bounds__(512, 4) void k_gate_fused(const float* __restrict__ h,
                                                       const unsigned short* __restrict__ u_t,
                                                       const float* __restrict__ tw_,
                                                       const float* __restrict__ v,
                                                       float* __restrict__ partial,
                                                       float* __restrict__ pm,
                                                       float* __restrict__ pd,
                                                       int S, int SC) {
    __shared__ unsigned short hbf[GM * E_DIM];  // 16 KB bf16, swizzled
    __shared__ float red[8][GM];                // 1 KB
    __shared__ float exw[GM];                   // 128 B
    __shared__ float pacc[8][E_DIM];            // 8 KB

    const int b   = blockIdx.y;
    const int sc  = blockIdx.x;
    const int tid = threadIdx.x;
    const int w   = tid >> 6;      // wave 0..7
    const int l   = tid & 63;      // lane
    const int lg  = l >> 4;        // k-group 0..3
    const int lc  = l & 15;        // row/col class 0..15
    const int f0w = w * 32;        // wave's f-range base

    char* ldsb = (char*)hbf;

    // ---- per-wave u-slice: 16 x bf16x8 = 64 VGPR, loaded once from L2 ----
    bf16x8 ub[8][2];   // [kt][n]
#pragma unroll
    for (int kt = 0; kt < 8; ++kt)
#pragma unroll
        for (int n = 0; n < 2; ++n)
            ub[kt][n] = *reinterpret_cast<const bf16x8*>(
                u_t + (size_t)(f0w + n * 16 + lc) * E_DIM + kt * 32 + lg * 8);

    // ---- stage h rows sc*32..+31 (each wave 4 rows), fp32 -> bf16, swizzled ----
    const float* hb = h + ((size_t)b * S + (size_t)sc * GM) * E_DIM;
    float4 st[4];
#pragma unroll
    for (int it = 0; it < 4; ++it)
        st[it] = *reinterpret_cast<const float4*>(hb + (size_t)(it * 8 + w) * E_DIM + l * 4);
#pragma unroll
    for (int it = 0; it < 4; ++it) {
        const int row = it * 8 + w;
        uint2 pk;
        pk.x = (unsigned)f2bf(st[it].x) | ((unsigned)f2bf(st[it].y) << 16);
        pk.y = (unsigned)f2bf(st[it].z) | ((unsigned)f2bf(st[it].w) << 16);
        *reinterpret_cast<uint2*>(ldsb + swz(row * 512 + l * 8)) = pk;
    }

    // ---- per-wave epilogue constants ----
    float tw_f[2], v_f[2];
#pragma unroll
    for (int n = 0; n < 2; ++n) {
        const int f = f0w + n * 16 + lc;
        tw_f[n] = tw_[b * E_DIM + f];
        v_f[n]  = v[f];
    }

    f32x4 acc[2][2];
#pragma unroll
    for (int m = 0; m < 2; ++m)
#pragma unroll
        for (int n = 0; n < 2; ++n)
            acc[m][n] = (f32x4){0.f, 0.f, 0.f, 0.f};

    __syncthreads();   // h tile ready

    // ---- K loop: 8 k-steps of 32; A from LDS, B from registers ----
#pragma unroll
    for (int kt = 0; kt < 8; ++kt) {
        bf16x8 af[2];
#pragma unroll
        for (int m = 0; m < 2; ++m)
            af[m] = *reinterpret_cast<const bf16x8*>(
                ldsb + swz((m * 16 + lc) * 512 + kt * 64 + lg * 16));
#pragma unroll
        for (int n = 0; n < 2; ++n) {
            acc[0][n] = __builtin_amdgcn_mfma_f32_16x16x32_bf16(af[0], ub[kt][n], acc[0][n], 0, 0, 0);
            acc[1][n] = __builtin_amdgcn_mfma_f32_16x16x32_bf16(af[1], ub[kt][n], acc[1][n], 0, 0, 0);
        }
    }

    // ---- gate epilogue: tanh(z+tw)*v, sum over wave's 32 f ----
    float part[2][4] = {};   // [m][i]; row = m*16 + lg*4 + i, col-class lc
#pragma unroll
    for (int n = 0; n < 2; ++n)
#pragma unroll
        for (int m = 0; m < 2; ++m)
#pragma unroll
            for (int i = 0; i < 4; ++i)
                part[m][i] += fast_tanh(acc[m][n][i] + tw_f[n]) * v_f[n];

#pragma unroll
    for (int off = 1; off < 16; off <<= 1)
#pragma unroll
        for (int m = 0; m < 2; ++m)
#pragma unroll
            for (int i = 0; i < 4; ++i)
                part[m][i] += __shfl_xor(part[m][i], off, 64);

    if (lc == 0) {
#pragma unroll
        for (int m = 0; m < 2; ++m)
#pragma unroll
            for (int i = 0; i < 4; ++i)
                red[w][m * 16 + lg * 4 + i] = part[m][i];
    }
    __syncthreads();   // red ready

    // ---- block softmax stats: lanes 0..31 of wave 0 own the 32 g values ----
    if (tid < GM) {
        float g = 0.f;
#pragma unroll
        for (int ww = 0; ww < 8; ++ww) g += red[ww][tid];
        float mx = g;
#pragma unroll
        for (int off = 1; off < 32; off <<= 1)
            mx = fmaxf(mx, __shfl_xor(mx, off, 64));
        const float ex = __expf(g - mx);
        float d = ex;
#pragma unroll
        for (int off = 1; off < 32; off <<= 1)
            d += __shfl_xor(d, off, 64);
        exw[tid] = ex;
        if (tid == 0) {
            pm[(size_t)b * SC + sc] = mx;
            pd[(size_t)b * SC + sc] = d;
        }
    }
    __syncthreads();   // exw ready

    // ---- weighted partial: wave w sums rows w*4..w*4+3; lane owns 4 e-cols ----
    f32x4 a4 = (f32x4){0.f, 0.f, 0.f, 0.f};
#pragma unroll
    for (int j = 0; j < 4; ++j) {
        const int row = w * 4 + j;
        const float ws = exw[row];
        const uint2 hv = *reinterpret_cast<const uint2*>(ldsb + swz(row * 512 + l * 8));
        a4[0] = fmaf(ws, bf2f((unsigned short)(hv.x & 0xffff)), a4[0]);
        a4[1] = fmaf(ws, bf2f((unsigned short)(hv.x >> 16)),    a4[1]);
        a4[2] = fmaf(ws, bf2f((unsigned short)(hv.y & 0xffff)), a4[2]);
        a4[3] = fmaf(ws, bf2f((unsigned short)(hv.y >> 16)),    a4[3]);
    }
    *reinterpret_cast<f32x4*>(&pacc[w][l * 4]) = a4;
    __syncthreads();   // pacc ready

    if (tid < E_DIM) {
        float p = 0.f;
#pragma unroll
        for (int ww = 0; ww < 8; ++ww) p += pacc[ww][tid];
        partial[((size_t)b * SC + sc) * E_DIM + tid] = p;
    }
}

// ---------------- Kernel 2: exact softmax merge across chunks ----------------
__global__ __launch_bounds__(256) void k_combine(const float* __restrict__ partial,
                                                 const float* __restrict__ pm,
                                                 const float* __restrict__ pd,
                                                 float* __restrict__ out,
                                                 int SC) {
    const int b = blockIdx.x, t = threadIdx.x;
    __shared__ float sm[128], sd[128];
    if (t < SC) {
        sm[t] = pm[(size_t)b * SC + t];
        sd[t] = pd[(size_t)b * SC + t];
    }
    __syncthreads();

    float M = -3.4e38f;
    for (int c = 0; c < SC; ++c) M = fmaxf(M, sm[c]);

    float num = 0.f, den = 0.f;
    for (int c = 0; c < SC; ++c) {
        const float s = __expf(sm[c] - M);
        den = fmaf(s, sd[c], den);
        num = fmaf(s, partial[((size_t)b * SC + c) * E_DIM + t], num);
    }
    out[(size_t)b * E_DIM + t] = num / den;
}

extern "C" void kernel_launch(void* const* d_in, const int* in_sizes, int n_in,
                              void* d_out, int out_size, void* d_ws, size_t ws_size,
                              hipStream_t stream) {
    const float* h     = (const float*)d_in[0];
    const float* theta = (const float*)d_in[1];
    const float* w     = (const float*)d_in[2];
    const float* v     = (const float*)d_in[3];
    const float* u     = (const float*)d_in[4];
    float* out = (float*)d_out;

    const int E = in_sizes[3];              // 256
    const int T = in_sizes[2] / E;          // 100
    const int B = in_sizes[1] / T;          // 64
    const int S = in_sizes[0] / (B * E);    // 2048
    const int SC = S / GM;                  // 64

    float* tw = (float*)d_ws;                                     // [B,E]
    unsigned short* u_t = (unsigned short*)(tw + (size_t)B * E);  // [E,E] bf16
    float* partial = (float*)(u_t + (size_t)E * E);               // [B,SC,E]
    float* pm = partial + (size_t)B * SC * E;                     // [B,SC]
    float* pd = pm + (size_t)B * SC;                              // [B,SC]

    k_prep<<<dim3(E + B), dim3(256), 0, stream>>>(u, theta, w, u_t, tw, T);
    k_gate_fused<<<dim3(SC, B), dim3(512), 0, stream>>>(h, u_t, tw, v, partial, pm, pd, S, SC);
    k_combine<<<dim3(B), dim3(256), 0, stream>>>(partial, pm, pd, out, SC);
}